// Round 2
// baseline (145.937 us; speedup 1.0000x reference)
//
#include <hip/hip_runtime.h>
#include <hip/hip_bf16.h>
#include <math.h>

#define NB 4
#define NN 128
#define NF 128
#define NS 5
#define NT 32
#define NL 2

typedef __hip_bfloat16 bf16;
typedef short bf16x8 __attribute__((ext_vector_type(8)));
typedef float f32x4 __attribute__((ext_vector_type(4)));

__device__ __forceinline__ float b2f(const bf16 x) { return __bfloat162float(x); }
__device__ __forceinline__ float fast_rcp(float x) { return __builtin_amdgcn_rcpf(x); }
__device__ __forceinline__ float fast_rsq(float x) { return __builtin_amdgcn_rsqf(x); }
__device__ __forceinline__ float silu_fast(float x) { return x * fast_rcp(1.0f + __expf(-x)); }
__device__ __forceinline__ float ldf(const void* p, int i, int fl) {
  return fl ? b2f(((const bf16*)p)[i]) : ((const float*)p)[i];
}
// float -> bf16 bits (RNE)
__device__ __forceinline__ short f2bf(float x) {
  unsigned u = __float_as_uint(x);
  unsigned r = (u + 0x7fffu + ((u >> 16) & 1u)) >> 16;
  return (short)r;
}

#define PI_F 3.14159265358979323846f
#define SQRT3_F 1.7320508075688772f

// converted-weights region offsets (floats) within d_ws after the flag slot
#define POS_OFF 0
#define GF_OFF  1536
#define WE_OFF  1664
#define BE_OFF  6400
#define WR1_OFF 6528
#define BR1_OFF 6656
#define WR2_OFF 6784
#define WN_OFF  72320
#define C1_OFF  105088
#define C2_OFF  106112
#define C3_OFF  107136
#define M0_OFF  108160
#define M1_OFF  140928
#define G1_OFF  173696
#define G2_OFF  177792
#define WV_OFF  181888
#define CVT_TOTAL 182144

// ---------------------------------------------------------------------------
// prep_convert: known-good; Ag zero-init and vec zero-init removed (no Ag
// buffer any more; layer-0 vec is handled as implicit zeros in fused kernel).
// ---------------------------------------------------------------------------
__global__ void prep_convert_kernel(
    const void* __restrict__ pos_raw, const int* __restrict__ nfeat,
    const void* __restrict__ gf,  const void* __restrict__ we,
    const void* __restrict__ be,  const void* __restrict__ wr1,
    const void* __restrict__ br1, const void* __restrict__ wr2,
    const void* __restrict__ wn,  const void* __restrict__ c1,
    const void* __restrict__ c2,  const void* __restrict__ c3,
    const void* __restrict__ m0,  const void* __restrict__ m1,
    const void* __restrict__ g1,  const void* __restrict__ g2,
    const void* __restrict__ wv,
    int* __restrict__ flag, float* __restrict__ cvt,
    float* __restrict__ pos_cur, float* __restrict__ z,
    float* __restrict__ env, short* __restrict__ pkw)
{
  __shared__ float posB[NN*3];
  __shared__ float scs[NF];
  __shared__ int sbad;
  const int tid = threadIdx.x;
  const int bn  = blockIdx.x;        // node row, 0..511
  const int b   = bn >> 7;
  const int n   = bn & 127;

  if (tid == 0) sbad = 0;
  __syncthreads();
  {
    const bf16* p = (const bf16*)pos_raw;
    int bad = 0;
    for (int i = tid; i < NB*NN*3; i += 256) {
      float v = b2f(p[i]);
      if (!(fabsf(v) <= 1024.0f)) bad = 1;   // NaN also fails
    }
    if (bad) sbad = 1;
  }
  __syncthreads();
  const int fl = sbad ? 0 : 1;               // 1 = bf16 inputs
  if (bn == 0 && tid == 0) *flag = fl;

  for (int i = bn*256 + tid; i < CVT_TOTAL; i += 512*256) {
    const void* src; int j;
    if      (i < GF_OFF)  { src = pos_raw; j = i - POS_OFF; }
    else if (i < WE_OFF)  { src = gf;  j = i - GF_OFF; }
    else if (i < BE_OFF)  { src = we;  j = i - WE_OFF; }
    else if (i < WR1_OFF) { src = be;  j = i - BE_OFF; }
    else if (i < BR1_OFF) { src = wr1; j = i - WR1_OFF; }
    else if (i < WN_OFF)  { src = br1; j = i - BR1_OFF; }
    else if (i < C1_OFF)  { src = wr2; j = i - WR2_OFF; }
    else if (i < C2_OFF)  { src = c1;  j = i - C1_OFF; }
    else if (i < C3_OFF)  { src = c2;  j = i - C2_OFF; }
    else if (i < M0_OFF)  { src = c3;  j = i - C3_OFF; }
    else if (i < M1_OFF)  { src = m0;  j = i - M0_OFF; }
    else if (i < G1_OFF)  { src = m1;  j = i - M1_OFF; }
    else if (i < G2_OFF)  { src = g1;  j = i - G1_OFF; }
    else if (i < WV_OFF)  { src = g2;  j = i - G2_OFF; }
    else                  { src = wv;  j = i - WV_OFF; }
    if (i < WN_OFF && i >= C1_OFF) { }       // (unreachable; keep structure)
    if      (i >= WN_OFF && i < C1_OFF) { src = wn; j = i - WN_OFF; }
    cvt[i] = fl ? b2f(((const bf16*)src)[j]) : ((const float*)src)[j];
  }

  // pack Wr2 cols into bf16 MFMA B-fragments, sqrt3 folded (known-good).
  if (bn < 16) {
    int gid  = bn*256 + tid;        // 0..4095
    int lyr  = gid >> 11;
    int r    = gid & 2047;
    int wv2  = r >> 9;
    int t    = (r >> 7) & 3;
    int ks   = (r >> 6) & 1;
    int lane = r & 63;
    int qq = lane >> 4, nn = lane & 15;
    int col = wv2*64 + t*16 + nn;
    short* dst = pkw + (size_t)gid*8;
    #pragma unroll
    for (int j = 0; j < 8; ++j) {
      int k = ks*32 + qq*8 + j;
      float v = ldf(wr2, lyr*64*512 + k*512 + col, fl);
      if (wv2 >= 2) v *= SQRT3_F;
      dst[j] = f2bf(v);
    }
  }

  for (int i = tid; i < NN*3; i += 256)
    posB[i] = ldf(pos_raw, b*NN*3 + i, fl);
  if (tid < 128) {
    int sp = nfeat[bn] - 1;
    float acc = ldf(we, sp*NF + tid, fl) + ldf(be, tid, fl);
    #pragma unroll 8
    for (int t = 0; t < NT; ++t)
      acc += ldf(gf, b*NT + t, fl) * ldf(we, (NS + t)*NF + tid, fl);
    scs[tid] = acc;
  }
  __syncthreads();

  if (tid < 128) {
    const int f = tid;
    {
      float px = posB[n*3+0], py = posB[n*3+1], pz = posB[n*3+2];
      float vx = px - posB[f*3+0];
      float vy = py - posB[f*3+1];
      float vz = pz - posB[f*3+2];
      float lng = sqrtf(vx*vx + vy*vy + vz*vz + 1e-12f);
      env[bn*NN + f] = (lng < 10.0f) ? 0.5f*(cosf(PI_F*lng*0.1f) + 1.0f) : 0.0f;
    }
    {
      float acc = 0.f;
      if (fl) {
        const bf16* W = (const bf16*)wn;
        #pragma unroll 8
        for (int k = 0; k < NF; ++k) acc += scs[k] * b2f(W[k*NF + f]);
      } else {
        const float* W = (const float*)wn;
        #pragma unroll 8
        for (int k = 0; k < NF; ++k) acc += scs[k] * W[k*NF + f];
      }
      z[bn*NF + f] = acc;
    }
    if (f < 3) pos_cur[bn*3 + f] = posB[n*3 + f];
  }
}

// ---------------------------------------------------------------------------
// FUSED edge+node v1: 512 blocks, each block owns ONE receiver node.
// Edge phase: A-tile rows = 16 senders of this receiver; 8 chunks cover all
// 128 senders; same MFMA+consume math as edge v10. Block ends holding the
// complete A[4][NF] for its node -> node phase (node v2 verbatim) runs in
// the same block from LDS. No atomics, no Ag buffer, 1 launch per layer.
// Inter-layer state double-buffered (pos0/pos1, z0/z1; vec only L0->L1).
// ---------------------------------------------------------------------------
__global__ __launch_bounds__(256, 2)
void fused_kernel(const float* __restrict__ posIn, float* __restrict__ posOut,
                  const float* __restrict__ zIn,  float* __restrict__ zOut,
                  const float* __restrict__ vecIn, float* __restrict__ vecOut,
                  const float* __restrict__ env,  const float* __restrict__ cvt,
                  const short* __restrict__ pk, int layer, int last,
                  const int* __restrict__ flag, void* __restrict__ out)
{
  union SM {                                        // 64 KB, phase-aliased
    float4 zvp[2][16][NF];                          // edge: (z,vec) staging
    struct {                                        // node: split-k scratch
      float P[8][32][17];
      float Pg[8][16];
      float scs[NF];
      float h16[16];
      float red[2][4];
    } nd;
  };
  __shared__ __align__(16) SM sm;
  __shared__ float posL[NN*3];                      // 1.5 KB
  __shared__ float envL[NN];                        // this receiver's env row
  __shared__ float w1L[64], b1L[64];
  __shared__ __align__(16) short hidA[2][16][72];   // 4.5 KB bf16 A tiles
  __shared__ __align__(16) float4 uenvL[2][16];     // per-edge (u, envw)
  __shared__ float Ash[4][NF];                      // completed A rows (2 KB)

  const int tid  = threadIdx.x;
  const int bidx = blockIdx.x;                      // b*128 + n
  const int b    = bidx >> 7;
  const int n    = bidx & 127;                      // this block's receiver

  const int wvid  = tid >> 6;                       // wave id 0..3
  const int lane  = tid & 63;
  const int n16   = lane & 15;                      // MFMA n / A-row index
  const int q     = lane >> 4;                      // quarter -> si group
  const int halfB = wvid >> 1;                      // 0: ell0 cols, 1: ell1

  // ---- prologue ----
  for (int i = tid; i < NN*3; i += 256)
    posL[i] = posIn[b*NN*3 + i];
  if (tid < 128) envL[tid] = env[(size_t)(b*NN + n)*NN + tid];
  if (tid < 64) {
    w1L[tid] = cvt[WR1_OFF + layer*64 + tid];
    b1L[tid] = cvt[BR1_OFF + layer*64 + tid];
  }
  bf16x8 bfr[4][2];                                 // packed Wr2 fragments
  {
    const bf16x8* PK = (const bf16x8*)pk + (size_t)layer*2048 + wvid*512 + lane;
    #pragma unroll
    for (int t = 0; t < 4; ++t) {
      #pragma unroll
      for (int ks = 0; ks < 2; ++ks)
        bfr[t][ks] = PK[(t*2 + ks)*64];
    }
  }
  float acR[12];
  #pragma unroll
  for (int i = 0; i < 12; ++i) acR[i] = 0.f;

  __syncthreads();   // posL/envL/w1L ready

  const float hrx = posL[n*3 + 0];
  const float hry = posL[n*3 + 1];
  const float hrz = posL[n*3 + 2];
  const float w1v = w1L[lane], b1v = b1L[lane];

  const int fS  = tid & 127;                        // staging column
  const int si0 = tid >> 7;                         // staging sender base

  float4 pv[8];                                     // prefetch registers

  // ---- stage chunk 0 (senders 0..15) ----
  #pragma unroll
  for (int rep = 0; rep < 8; ++rep) {
    int sl = si0 + 2*rep;
    int gs = b*NN + sl;
    pv[rep].x = zIn[gs*NF + fS];
    if (layer) {
      pv[rep].y = vecIn[((size_t)gs*3 + 0)*NF + fS];
      pv[rep].z = vecIn[((size_t)gs*3 + 1)*NF + fS];
      pv[rep].w = vecIn[((size_t)gs*3 + 2)*NF + fS];
    } else { pv[rep].y = 0.f; pv[rep].z = 0.f; pv[rep].w = 0.f; }
  }
  #pragma unroll
  for (int j = 0; j < 4; ++j) {
    int si = wvid*4 + j;
    int s  = si;                                    // chunk 0
    float vx = hrx - posL[s*3 + 0];
    float vy = hry - posL[s*3 + 1];
    float vz = hrz - posL[s*3 + 2];
    float d = vx*vx + vy*vy + vz*vz + 1e-12f;
    float lng = d * fast_rsq(d);
    hidA[0][si][lane] = f2bf(silu_fast(lng * w1v + b1v));
  }
  if (tid < 16) {
    int s = tid;
    float vx = hrx - posL[s*3 + 0];                 // tid<16 lanes: wvid==0
    float vy = hry - posL[s*3 + 1];
    float vz = hrz - posL[s*3 + 2];
    float d = vx*vx + vy*vy + vz*vz + 1e-12f;
    float inv = fast_rsq(d);
    float envw = (s == n) ? 0.f : envL[s] * 0.0625f;
    uenvL[0][tid] = make_float4(vx*inv, vy*inv, vz*inv, envw);
  }
  #pragma unroll
  for (int rep = 0; rep < 8; ++rep)
    sm.zvp[0][si0 + 2*rep][fS] = pv[rep];
  __syncthreads();

  // ---- pipelined chunk loop: 1 barrier per chunk, 8 chunks x 16 senders ----
  #pragma unroll 2
  for (int c = 0; c < 8; ++c) {
    const int cb = c & 1, nb = cb ^ 1;
    const int nc0 = (c + 1) * 16;

    // issue next chunk's global loads first (latency hidden under MFMA)
    if (c < 7) {
      #pragma unroll
      for (int rep = 0; rep < 8; ++rep) {
        int gs = b*NN + nc0 + si0 + 2*rep;
        pv[rep].x = zIn[gs*NF + fS];
        if (layer) {
          pv[rep].y = vecIn[((size_t)gs*3 + 0)*NF + fS];
          pv[rep].z = vecIn[((size_t)gs*3 + 1)*NF + fS];
          pv[rep].w = vecIn[((size_t)gs*3 + 2)*NF + fS];
        } else { pv[rep].y = 0.f; pv[rep].z = 0.f; pv[rep].w = 0.f; }
      }
    }

    // ---- MFMA radial GEMM + consume (buffer cb) ----
    bf16x8 af0 = *(const bf16x8*)&hidA[cb][n16][q*8];
    bf16x8 af1 = *(const bf16x8*)&hidA[cb][n16][q*8 + 32];
    float4 ue[4];
    #pragma unroll
    for (int r = 0; r < 4; ++r) ue[r] = uenvL[cb][q*4 + r];

    #pragma unroll
    for (int t = 0; t < 4; ++t) {
      f32x4 Cf = {0.f, 0.f, 0.f, 0.f};
      Cf = __builtin_amdgcn_mfma_f32_16x16x32_bf16(af0, bfr[t][0], Cf, 0, 0, 0);
      Cf = __builtin_amdgcn_mfma_f32_16x16x32_bf16(af1, bfr[t][1], Cf, 0, 0, 0);
      int f = (wvid*64 + t*16 + n16) & 127;         // feature index
      if (!halfB) {
        float a0 = 0.f;
        #pragma unroll
        for (int r = 0; r < 4; ++r) {               // C row = q*4+r = si
          float4 zv = sm.zvp[cb][q*4 + r][f];
          float fv = zv.x + ue[r].x*zv.y + ue[r].y*zv.z + ue[r].z*zv.w;
          a0 += (Cf[r] * ue[r].w) * fv;
        }
        acR[t] += a0;
      } else {
        float t1 = 0.f, t2 = 0.f, t3 = 0.f;
        #pragma unroll
        for (int r = 0; r < 4; ++r) {
          float4 zv = sm.zvp[cb][q*4 + r][f];
          float fv = zv.x + ue[r].x*zv.y + ue[r].y*zv.z + ue[r].z*zv.w;
          float tt = (Cf[r] * ue[r].w) * fv;        // sqrt3 folded into B
          t1 += tt * ue[r].x;
          t2 += tt * ue[r].y;
          t3 += tt * ue[r].z;
        }
        acR[t*3 + 0] += t1;
        acR[t*3 + 1] += t2;
        acR[t*3 + 2] += t3;
      }
    }

    // ---- stage next chunk into buffer nb ----
    if (c < 7) {
      #pragma unroll
      for (int j = 0; j < 4; ++j) {
        int si = wvid*4 + j;
        int s  = nc0 + si;
        float vx = hrx - posL[s*3 + 0];
        float vy = hry - posL[s*3 + 1];
        float vz = hrz - posL[s*3 + 2];
        float d = vx*vx + vy*vy + vz*vz + 1e-12f;
        float lng = d * fast_rsq(d);
        hidA[nb][si][lane] = f2bf(silu_fast(lng * w1v + b1v));
      }
      if (tid < 16) {
        int s = nc0 + tid;
        float vx = hrx - posL[s*3 + 0];
        float vy = hry - posL[s*3 + 1];
        float vz = hrz - posL[s*3 + 2];
        float d = vx*vx + vy*vy + vz*vz + 1e-12f;
        float inv = fast_rsq(d);
        float envw = (s == n) ? 0.f : envL[s] * 0.0625f;
        uenvL[nb][tid] = make_float4(vx*inv, vy*inv, vz*inv, envw);
      }
      #pragma unroll
      for (int rep = 0; rep < 8; ++rep)
        sm.zvp[nb][si0 + 2*rep][fS] = pv[rep];
    }
    __syncthreads();
  }

  // ---- edge epilogue: cross-quarter reduce, write complete A to LDS ----
  #pragma unroll
  for (int i = 0; i < 12; ++i) {
    float v = acR[i];
    v += __shfl_xor(v, 16, 64);
    v += __shfl_xor(v, 32, 64);
    acR[i] = v;
  }
  if (lane < 16) {
    #pragma unroll
    for (int t = 0; t < 4; ++t) {
      int f = (wvid*64 + t*16 + lane) & 127;
      if (!halfB) {
        Ash[0][f] = acR[t];
      } else {
        Ash[1][f] = acR[t*3 + 0];
        Ash[2][f] = acR[t*3 + 1];
        Ash[3][f] = acR[t*3 + 2];
      }
    }
  }
  __syncthreads();

  // ========================= node phase (node v2) =========================
  const int fn = tid & 127;
  float v0 = 0.f, v1 = 0.f, v2 = 0.f;

  // ---- phase 1: correlation gate (in-place on Ash) ----
  if (tid < 128) {
    float a0 = Ash[0][fn];
    float a1 = Ash[1][fn];
    float a2 = Ash[2][fn];
    float a3 = Ash[3][fn];
    float n0 = a0*a0;
    float C1 = cvt[C1_OFF + (layer*4 + 0)*NF + fn];
    float C2 = cvt[C2_OFF + (layer*4 + 0)*NF + fn];
    float C3 = cvt[C3_OFF + (layer*4 + 0)*NF + fn];
    float g0 = 1.0f + C1*n0 + C2*n0*n0 + C3*n0*n0*n0;
    float n1 = a1*a1 + a2*a2 + a3*a3;
    float D1 = cvt[C1_OFF + (layer*4 + 1)*NF + fn];
    float D2 = cvt[C2_OFF + (layer*4 + 1)*NF + fn];
    float D3 = cvt[C3_OFF + (layer*4 + 1)*NF + fn];
    float g1 = 1.0f + D1*n1 + D2*n1*n1 + D3*n1*n1*n1;
    Ash[0][fn] = a0 * g0;
    Ash[1][fn] = a1 * g1;
    Ash[2][fn] = a2 * g1;
    Ash[3][fn] = a3 * g1;
  }
  __syncthreads();

  // ---- phase 2: split-k GEMV vs M0 (scalar) and M1 (vector x3) ----
  {
    const float* M0 = cvt + M0_OFF + layer*NF*NF;
    const float* M1 = cvt + M1_OFF + layer*NF*NF;
    const int kh = tid >> 5;        // 0..7
    const int fq = tid & 31;        // f quad: f0 = fq*4
    float s0=0.f,s1=0.f,s2=0.f,s3=0.f;
    float w00=0.f,w01=0.f,w02=0.f,w03=0.f;
    float w10=0.f,w11=0.f,w12=0.f,w13=0.f;
    float w20=0.f,w21=0.f,w22=0.f,w23=0.f;
    #pragma unroll 4
    for (int kk = 0; kk < 16; ++kk) {
      int k = kh*16 + kk;
      float a0 = Ash[0][k], a1 = Ash[1][k], a2 = Ash[2][k], a3 = Ash[3][k];
      float4 m0 = *(const float4*)(M0 + k*NF + fq*4);
      float4 m1 = *(const float4*)(M1 + k*NF + fq*4);
      s0 += a0*m0.x; s1 += a0*m0.y; s2 += a0*m0.z; s3 += a0*m0.w;
      w00 += a1*m1.x; w01 += a1*m1.y; w02 += a1*m1.z; w03 += a1*m1.w;
      w10 += a2*m1.x; w11 += a2*m1.y; w12 += a2*m1.z; w13 += a2*m1.w;
      w20 += a3*m1.x; w21 += a3*m1.y; w22 += a3*m1.z; w23 += a3*m1.w;
    }
    float* Pp = &sm.nd.P[kh][fq][0];
    Pp[0]=s0;  Pp[1]=s1;  Pp[2]=s2;  Pp[3]=s3;
    Pp[4]=w00; Pp[5]=w01; Pp[6]=w02; Pp[7]=w03;
    Pp[8]=w10; Pp[9]=w11; Pp[10]=w12; Pp[11]=w13;
    Pp[12]=w20; Pp[13]=w21; Pp[14]=w22; Pp[15]=w23;
  }
  __syncthreads();

  // ---- phase 3: combine partials; scs + per-thread v0..v2 ----
  if (tid < 128) {
    int fq = fn >> 2, j = fn & 3;
    float sn = 0.f;
    #pragma unroll
    for (int kh = 0; kh < 8; ++kh) {
      const float* Pp = &sm.nd.P[kh][fq][0];
      sn += Pp[j];
      v0 += Pp[4 + j];
      v1 += Pp[8 + j];
      v2 += Pp[12 + j];
    }
    sm.nd.scs[fn] = sn;
  }
  __syncthreads();

  // ---- phase 4: z-GEMV for next layer (split-k) + G1 partials ----
  if (!last) {
    const float* W = cvt + WN_OFF + (layer+1)*NF*NF;
    const int kh = tid >> 5;
    const int fq = tid & 31;
    float s0=0.f,s1=0.f,s2=0.f,s3=0.f;
    #pragma unroll 4
    for (int kk = 0; kk < 16; ++kk) {
      int k = kh*16 + kk;
      float a = sm.nd.scs[k];
      float4 m = *(const float4*)(W + k*NF + fq*4);
      s0 += a*m.x; s1 += a*m.y; s2 += a*m.z; s3 += a*m.w;
    }
    float* Pp = &sm.nd.P[kh][fq][0];
    Pp[0]=s0; Pp[1]=s1; Pp[2]=s2; Pp[3]=s3;
  }
  if (tid < 128) {
    const float* G1 = cvt + G1_OFF + layer*NF*16;
    int o = tid & 15, g = tid >> 4;   // 8 k-groups x 16 outputs
    float acc = 0.f;
    #pragma unroll
    for (int kk = 0; kk < 16; ++kk) {
      int k = g*16 + kk;
      acc += sm.nd.scs[k] * G1[k*16 + o];
    }
    sm.nd.Pg[g][o] = acc;
  }
  __syncthreads();

  if (!last && tid < 128) {
    int fq = fn >> 2, j = fn & 3;
    float acc = 0.f;
    #pragma unroll
    for (int kh = 0; kh < 8; ++kh) acc += sm.nd.P[kh][fq][j];
    zOut[bidx*NF + fn] = acc;
  }
  if (tid < 16) {
    float acc = 0.f;
    #pragma unroll
    for (int g = 0; g < 8; ++g) acc += sm.nd.Pg[g][tid];
    sm.nd.h16[tid] = silu_fast(acc);
  }
  __syncthreads();

  // ---- phase 6: gate, vec write, equivariant position update ----
  if (tid < 128) {
    const float* G2 = cvt + G2_OFF + layer*16*NF;
    float gate = 0.f;
    #pragma unroll
    for (int j = 0; j < 16; ++j)
      gate += sm.nd.h16[j] * G2[j*NF + fn];
    float gv = gate * cvt[WV_OFF + layer*NF + fn];

    if (!last) {
      vecOut[((size_t)bidx*3 + 0)*NF + fn] = v0;
      vecOut[((size_t)bidx*3 + 1)*NF + fn] = v1;
      vecOut[((size_t)bidx*3 + 2)*NF + fn] = v2;
    }

    float p0 = v0*gv, p1 = v1*gv, p2 = v2*gv;
    #pragma unroll
    for (int off = 32; off > 0; off >>= 1) {
      p0 += __shfl_down(p0, off, 64);
      p1 += __shfl_down(p1, off, 64);
      p2 += __shfl_down(p2, off, 64);
    }
    int wave = fn >> 6;
    if ((fn & 63) == 0) {
      sm.nd.red[wave][0] = p0;
      sm.nd.red[wave][1] = p1;
      sm.nd.red[wave][2] = p2;
    }
  }
  __syncthreads();
  if (tid == 0) {
    float m0 = sm.nd.red[0][0] + sm.nd.red[1][0];
    float m1 = sm.nd.red[0][1] + sm.nd.red[1][1];
    float m2 = sm.nd.red[0][2] + sm.nd.red[1][2];
    float px = posL[n*3+0] + m0;
    float py = posL[n*3+1] + m1;
    float pz = posL[n*3+2] + m2;
    if (!last) {
      posOut[bidx*3+0] = px;
      posOut[bidx*3+1] = py;
      posOut[bidx*3+2] = pz;
    } else {
      float ox = px - cvt[POS_OFF + bidx*3+0];
      float oy = py - cvt[POS_OFF + bidx*3+1];
      float oz = pz - cvt[POS_OFF + bidx*3+2];
      if (*flag) {
        bf16* o = (bf16*)out;
        o[bidx*3+0] = __float2bfloat16(ox);
        o[bidx*3+1] = __float2bfloat16(oy);
        o[bidx*3+2] = __float2bfloat16(oz);
      } else {
        float* o = (float*)out;
        o[bidx*3+0] = ox;
        o[bidx*3+1] = oy;
        o[bidx*3+2] = oz;
      }
    }
  }
}

// ---------------------------------------------------------------------------
extern "C" void kernel_launch(void* const* d_in, const int* in_sizes, int n_in,
                              void* d_out, int out_size, void* d_ws, size_t ws_size,
                              hipStream_t stream)
{
  (void)in_sizes; (void)n_in; (void)out_size; (void)ws_size;
  const int* nfeat = (const int*)d_in[1];

  float* ws   = (float*)d_ws;
  int*   flag = (int*)ws;                     // 16 floats reserved
  float* cvt  = ws + 16;                      // CVT_TOTAL floats
  float* pos0 = cvt + CVT_TOTAL;              // 1536
  float* pos1 = pos0 + NB*NN*3;               // 1536
  float* z0   = pos1 + NB*NN*3;               // 65536
  float* z1   = z0 + NB*NN*NF;                // 65536
  float* vec1 = z1 + NB*NN*NF;                // 196608 (L0 node -> L1 edge)
  float* env  = vec1 + NB*NN*3*NF;            // 65536
  short* pk   = (short*)(env + NB*NN*NN);     // 32768 shorts (16B aligned)

  prep_convert_kernel<<<512, 256, 0, stream>>>(
      d_in[0], nfeat, d_in[2], d_in[3], d_in[4], d_in[5], d_in[6], d_in[7],
      d_in[8], d_in[9], d_in[10], d_in[11], d_in[12], d_in[13], d_in[14],
      d_in[15], d_in[16], flag, cvt, pos0, z0, env, pk);

  fused_kernel<<<512, 256, 0, stream>>>(pos0, pos1, z0, z1, (const float*)0,
                                        vec1, env, cvt, pk, 0, 0, flag, d_out);
  fused_kernel<<<512, 256, 0, stream>>>(pos1, (float*)0, z1, (float*)0, vec1,
                                        (float*)0, env, cvt, pk, 1, 1, flag, d_out);
}

// Round 3
// 141.838 us; speedup vs baseline: 1.0289x; 1.0289x over previous
//
#include <hip/hip_runtime.h>
#include <hip/hip_bf16.h>
#include <math.h>

#define NB 4
#define NN 128
#define NF 128
#define NS 5
#define NT 32
#define NL 2

typedef __hip_bfloat16 bf16;
typedef short bf16x8 __attribute__((ext_vector_type(8)));
typedef float f32x4 __attribute__((ext_vector_type(4)));

typedef const void __attribute__((address_space(1))) gv_t;
typedef void __attribute__((address_space(3))) lv_t;

__device__ __forceinline__ float b2f(const bf16 x) { return __bfloat162float(x); }
__device__ __forceinline__ float fast_rcp(float x) { return __builtin_amdgcn_rcpf(x); }
__device__ __forceinline__ float fast_rsq(float x) { return __builtin_amdgcn_rsqf(x); }
__device__ __forceinline__ float silu_fast(float x) { return x * fast_rcp(1.0f + __expf(-x)); }
__device__ __forceinline__ float ldf(const void* p, int i, int fl) {
  return fl ? b2f(((const bf16*)p)[i]) : ((const float*)p)[i];
}
// float -> bf16 bits (RNE)
__device__ __forceinline__ short f2bf(float x) {
  unsigned u = __float_as_uint(x);
  unsigned r = (u + 0x7fffu + ((u >> 16) & 1u)) >> 16;
  return (short)r;
}
// global->LDS 16B DMA: wave-uniform LDS base, per-lane global addr (m03/m97)
__device__ __forceinline__ void gload16(const float4* g, float4* l) {
  __builtin_amdgcn_global_load_lds((gv_t*)g, (lv_t*)l, 16, 0, 0);
}

#define PI_F 3.14159265358979323846f
#define SQRT3_F 1.7320508075688772f

// converted-weights region offsets (floats) within d_ws after the flag slot
#define POS_OFF 0
#define GF_OFF  1536
#define WE_OFF  1664
#define BE_OFF  6400
#define WR1_OFF 6528
#define BR1_OFF 6656
#define WR2_OFF 6784
#define WN_OFF  72320
#define C1_OFF  105088
#define C2_OFF  106112
#define C3_OFF  107136
#define M0_OFF  108160
#define M1_OFF  140928
#define G1_OFF  173696
#define G2_OFF  177792
#define WV_OFF  181888
#define CVT_TOTAL 182144

// ---------------------------------------------------------------------------
// prep_convert: if-chain restored to the correct (round-1) mapping — round-2
// version read br1 out-of-bounds for the (dead) cvt Wr2 region. z output is
// now an interleaved float4 buffer zv[node][f] = {z, 0, 0, 0}.
// ---------------------------------------------------------------------------
__global__ void prep_convert_kernel(
    const void* __restrict__ pos_raw, const int* __restrict__ nfeat,
    const void* __restrict__ gf,  const void* __restrict__ we,
    const void* __restrict__ be,  const void* __restrict__ wr1,
    const void* __restrict__ br1, const void* __restrict__ wr2,
    const void* __restrict__ wn,  const void* __restrict__ c1,
    const void* __restrict__ c2,  const void* __restrict__ c3,
    const void* __restrict__ m0,  const void* __restrict__ m1,
    const void* __restrict__ g1,  const void* __restrict__ g2,
    const void* __restrict__ wv,
    int* __restrict__ flag, float* __restrict__ cvt,
    float* __restrict__ pos_cur, float4* __restrict__ zv,
    float* __restrict__ env, short* __restrict__ pkw)
{
  __shared__ float posB[NN*3];
  __shared__ float scs[NF];
  __shared__ int sbad;
  const int tid = threadIdx.x;
  const int bn  = blockIdx.x;        // node row, 0..511
  const int b   = bn >> 7;
  const int n   = bn & 127;

  if (tid == 0) sbad = 0;
  __syncthreads();
  {
    const bf16* p = (const bf16*)pos_raw;
    int bad = 0;
    for (int i = tid; i < NB*NN*3; i += 256) {
      float v = b2f(p[i]);
      if (!(fabsf(v) <= 1024.0f)) bad = 1;   // NaN also fails
    }
    if (bad) sbad = 1;
  }
  __syncthreads();
  const int fl = sbad ? 0 : 1;               // 1 = bf16 inputs
  if (bn == 0 && tid == 0) *flag = fl;

  for (int i = bn*256 + tid; i < CVT_TOTAL; i += 512*256) {
    const void* src; int j;
    if      (i < GF_OFF)  { src = pos_raw; j = i - POS_OFF; }
    else if (i < WE_OFF)  { src = gf;  j = i - GF_OFF; }
    else if (i < BE_OFF)  { src = we;  j = i - WE_OFF; }
    else if (i < WR1_OFF) { src = be;  j = i - BE_OFF; }
    else if (i < BR1_OFF) { src = wr1; j = i - WR1_OFF; }
    else if (i < WR2_OFF) { src = br1; j = i - BR1_OFF; }
    else if (i < WN_OFF)  { src = wr2; j = i - WR2_OFF; }
    else if (i < C1_OFF)  { src = wn;  j = i - WN_OFF; }
    else if (i < C2_OFF)  { src = c1;  j = i - C1_OFF; }
    else if (i < C3_OFF)  { src = c2;  j = i - C2_OFF; }
    else if (i < M0_OFF)  { src = c3;  j = i - C3_OFF; }
    else if (i < M1_OFF)  { src = m0;  j = i - M0_OFF; }
    else if (i < G1_OFF)  { src = m1;  j = i - M1_OFF; }
    else if (i < G2_OFF)  { src = g1;  j = i - G1_OFF; }
    else if (i < WV_OFF)  { src = g2;  j = i - G2_OFF; }
    else                  { src = wv;  j = i - WV_OFF; }
    cvt[i] = fl ? b2f(((const bf16*)src)[j]) : ((const float*)src)[j];
  }

  // pack Wr2 cols into bf16 MFMA B-fragments, sqrt3 folded (known-good).
  if (bn < 16) {
    int gid  = bn*256 + tid;        // 0..4095
    int lyr  = gid >> 11;
    int r    = gid & 2047;
    int wv2  = r >> 9;
    int t    = (r >> 7) & 3;
    int ks   = (r >> 6) & 1;
    int lane = r & 63;
    int qq = lane >> 4, nn = lane & 15;
    int col = wv2*64 + t*16 + nn;
    short* dst = pkw + (size_t)gid*8;
    #pragma unroll
    for (int j = 0; j < 8; ++j) {
      int k = ks*32 + qq*8 + j;
      float v = ldf(wr2, lyr*64*512 + k*512 + col, fl);
      if (wv2 >= 2) v *= SQRT3_F;
      dst[j] = f2bf(v);
    }
  }

  for (int i = tid; i < NN*3; i += 256)
    posB[i] = ldf(pos_raw, b*NN*3 + i, fl);
  if (tid < 128) {
    int sp = nfeat[bn] - 1;
    float acc = ldf(we, sp*NF + tid, fl) + ldf(be, tid, fl);
    #pragma unroll 8
    for (int t = 0; t < NT; ++t)
      acc += ldf(gf, b*NT + t, fl) * ldf(we, (NS + t)*NF + tid, fl);
    scs[tid] = acc;
  }
  __syncthreads();

  if (tid < 128) {
    const int f = tid;
    {
      float px = posB[n*3+0], py = posB[n*3+1], pz = posB[n*3+2];
      float vx = px - posB[f*3+0];
      float vy = py - posB[f*3+1];
      float vz = pz - posB[f*3+2];
      float lng = sqrtf(vx*vx + vy*vy + vz*vz + 1e-12f);
      env[bn*NN + f] = (lng < 10.0f) ? 0.5f*(cosf(PI_F*lng*0.1f) + 1.0f) : 0.0f;
    }
    {
      float acc = 0.f;
      if (fl) {
        const bf16* W = (const bf16*)wn;
        #pragma unroll 8
        for (int k = 0; k < NF; ++k) acc += scs[k] * b2f(W[k*NF + f]);
      } else {
        const float* W = (const float*)wn;
        #pragma unroll 8
        for (int k = 0; k < NF; ++k) acc += scs[k] * W[k*NF + f];
      }
      zv[(size_t)bn*NF + f] = make_float4(acc, 0.f, 0.f, 0.f);  // layer-0 vec=0
    }
    if (f < 3) pos_cur[bn*3 + f] = posB[n*3 + f];
  }
}

// ---------------------------------------------------------------------------
// FUSED edge+node v2: zv = interleaved {z, vec0, vec1, vec2} float4 buffer;
// edge staging is 8x global_load_lds(16B) per thread per chunk (DMA straight
// into the linear zvp tile — no pv registers, no ds_writes, no layer branch).
// Everything else identical to fused v1 (passed, absmax 2e-3).
// ---------------------------------------------------------------------------
__global__ __launch_bounds__(256, 2)
void fused_kernel(const float* __restrict__ posIn, float* __restrict__ posOut,
                  const float4* __restrict__ zvIn, float4* __restrict__ zvOut,
                  const float* __restrict__ env,  const float* __restrict__ cvt,
                  const short* __restrict__ pk, int layer, int last,
                  const int* __restrict__ flag, void* __restrict__ out)
{
  union SM {                                        // 64 KB, phase-aliased
    float4 zvp[2][16][NF];                          // edge: (z,vec) staging
    struct {                                        // node: split-k scratch
      float P[8][32][17];
      float Pg[8][16];
      float scs[NF];
      float h16[16];
      float red[2][4];
    } nd;
  };
  __shared__ __align__(16) SM sm;
  __shared__ float posL[NN*3];                      // 1.5 KB
  __shared__ float envL[NN];                        // this receiver's env row
  __shared__ float w1L[64], b1L[64];
  __shared__ __align__(16) short hidA[2][16][72];   // 4.5 KB bf16 A tiles
  __shared__ __align__(16) float4 uenvL[2][16];     // per-edge (u, envw)
  __shared__ float Ash[4][NF];                      // completed A rows (2 KB)

  const int tid  = threadIdx.x;
  const int bidx = blockIdx.x;                      // b*128 + n
  const int b    = bidx >> 7;
  const int n    = bidx & 127;                      // this block's receiver

  const int wvid  = tid >> 6;                       // wave id 0..3
  const int lane  = tid & 63;
  const int n16   = lane & 15;                      // MFMA n / A-row index
  const int q     = lane >> 4;                      // quarter -> si group
  const int halfB = wvid >> 1;                      // 0: ell0 cols, 1: ell1

  // ---- issue chunk-0 zv staging DMA immediately (no dependencies) ----
  {
    const float4* g = zvIn + (size_t)b*NN*NF + wvid*64 + lane;
    float4* l = &sm.zvp[0][0][0] + wvid*64;
    #pragma unroll
    for (int rep = 0; rep < 8; ++rep)
      gload16(g + rep*256, l + rep*256);
  }

  // ---- prologue ----
  for (int i = tid; i < NN*3; i += 256)
    posL[i] = posIn[b*NN*3 + i];
  if (tid < 128) envL[tid] = env[(size_t)(b*NN + n)*NN + tid];
  if (tid < 64) {
    w1L[tid] = cvt[WR1_OFF + layer*64 + tid];
    b1L[tid] = cvt[BR1_OFF + layer*64 + tid];
  }
  bf16x8 bfr[4][2];                                 // packed Wr2 fragments
  {
    const bf16x8* PK = (const bf16x8*)pk + (size_t)layer*2048 + wvid*512 + lane;
    #pragma unroll
    for (int t = 0; t < 4; ++t) {
      #pragma unroll
      for (int ks = 0; ks < 2; ++ks)
        bfr[t][ks] = PK[(t*2 + ks)*64];
    }
  }
  float acR[12];
  #pragma unroll
  for (int i = 0; i < 12; ++i) acR[i] = 0.f;

  __syncthreads();   // posL/envL/w1L ready; chunk-0 DMA drained (vmcnt)

  const float hrx = posL[n*3 + 0];
  const float hry = posL[n*3 + 1];
  const float hrz = posL[n*3 + 2];
  const float w1v = w1L[lane], b1v = b1L[lane];

  // ---- stage chunk-0 hidA / uenv ----
  #pragma unroll
  for (int j = 0; j < 4; ++j) {
    int si = wvid*4 + j;
    int s  = si;                                    // chunk 0
    float vx = hrx - posL[s*3 + 0];
    float vy = hry - posL[s*3 + 1];
    float vz = hrz - posL[s*3 + 2];
    float d = vx*vx + vy*vy + vz*vz + 1e-12f;
    float lng = d * fast_rsq(d);
    hidA[0][si][lane] = f2bf(silu_fast(lng * w1v + b1v));
  }
  if (tid < 16) {
    int s = tid;
    float vx = hrx - posL[s*3 + 0];
    float vy = hry - posL[s*3 + 1];
    float vz = hrz - posL[s*3 + 2];
    float d = vx*vx + vy*vy + vz*vz + 1e-12f;
    float inv = fast_rsq(d);
    float envw = (s == n) ? 0.f : envL[s] * 0.0625f;
    uenvL[0][tid] = make_float4(vx*inv, vy*inv, vz*inv, envw);
  }
  __syncthreads();

  // ---- pipelined chunk loop: 1 barrier per chunk, 8 chunks x 16 senders ----
  #pragma unroll 2
  for (int c = 0; c < 8; ++c) {
    const int cb = c & 1, nb = cb ^ 1;
    const int nc0 = (c + 1) * 16;

    // issue next chunk's global->LDS DMA first (hidden under MFMA+consume)
    if (c < 7) {
      const float4* g = zvIn + ((size_t)b*NN + nc0)*NF + wvid*64 + lane;
      float4* l = &sm.zvp[nb][0][0] + wvid*64;
      #pragma unroll
      for (int rep = 0; rep < 8; ++rep)
        gload16(g + rep*256, l + rep*256);
    }

    // ---- MFMA radial GEMM + consume (buffer cb) ----
    bf16x8 af0 = *(const bf16x8*)&hidA[cb][n16][q*8];
    bf16x8 af1 = *(const bf16x8*)&hidA[cb][n16][q*8 + 32];
    float4 ue[4];
    #pragma unroll
    for (int r = 0; r < 4; ++r) ue[r] = uenvL[cb][q*4 + r];

    #pragma unroll
    for (int t = 0; t < 4; ++t) {
      f32x4 Cf = {0.f, 0.f, 0.f, 0.f};
      Cf = __builtin_amdgcn_mfma_f32_16x16x32_bf16(af0, bfr[t][0], Cf, 0, 0, 0);
      Cf = __builtin_amdgcn_mfma_f32_16x16x32_bf16(af1, bfr[t][1], Cf, 0, 0, 0);
      int f = (wvid*64 + t*16 + n16) & 127;         // feature index
      if (!halfB) {
        float a0 = 0.f;
        #pragma unroll
        for (int r = 0; r < 4; ++r) {               // C row = q*4+r = si
          float4 zv = sm.zvp[cb][q*4 + r][f];
          float fv = zv.x + ue[r].x*zv.y + ue[r].y*zv.z + ue[r].z*zv.w;
          a0 += (Cf[r] * ue[r].w) * fv;
        }
        acR[t] += a0;
      } else {
        float t1 = 0.f, t2 = 0.f, t3 = 0.f;
        #pragma unroll
        for (int r = 0; r < 4; ++r) {
          float4 zv = sm.zvp[cb][q*4 + r][f];
          float fv = zv.x + ue[r].x*zv.y + ue[r].y*zv.z + ue[r].z*zv.w;
          float tt = (Cf[r] * ue[r].w) * fv;        // sqrt3 folded into B
          t1 += tt * ue[r].x;
          t2 += tt * ue[r].y;
          t3 += tt * ue[r].z;
        }
        acR[t*3 + 0] += t1;
        acR[t*3 + 1] += t2;
        acR[t*3 + 2] += t3;
      }
    }

    // ---- stage next chunk's hidA / uenv into buffer nb ----
    if (c < 7) {
      #pragma unroll
      for (int j = 0; j < 4; ++j) {
        int si = wvid*4 + j;
        int s  = nc0 + si;
        float vx = hrx - posL[s*3 + 0];
        float vy = hry - posL[s*3 + 1];
        float vz = hrz - posL[s*3 + 2];
        float d = vx*vx + vy*vy + vz*vz + 1e-12f;
        float lng = d * fast_rsq(d);
        hidA[nb][si][lane] = f2bf(silu_fast(lng * w1v + b1v));
      }
      if (tid < 16) {
        int s = nc0 + tid;
        float vx = hrx - posL[s*3 + 0];
        float vy = hry - posL[s*3 + 1];
        float vz = hrz - posL[s*3 + 2];
        float d = vx*vx + vy*vy + vz*vz + 1e-12f;
        float inv = fast_rsq(d);
        float envw = (s == n) ? 0.f : envL[s] * 0.0625f;
        uenvL[nb][tid] = make_float4(vx*inv, vy*inv, vz*inv, envw);
      }
    }
    __syncthreads();   // drains gloads (vmcnt) + hidA/uenv ds_writes
  }

  // ---- edge epilogue: cross-quarter reduce, write complete A to LDS ----
  #pragma unroll
  for (int i = 0; i < 12; ++i) {
    float v = acR[i];
    v += __shfl_xor(v, 16, 64);
    v += __shfl_xor(v, 32, 64);
    acR[i] = v;
  }
  if (lane < 16) {
    #pragma unroll
    for (int t = 0; t < 4; ++t) {
      int f = (wvid*64 + t*16 + lane) & 127;
      if (!halfB) {
        Ash[0][f] = acR[t];
      } else {
        Ash[1][f] = acR[t*3 + 0];
        Ash[2][f] = acR[t*3 + 1];
        Ash[3][f] = acR[t*3 + 2];
      }
    }
  }
  __syncthreads();

  // ========================= node phase (node v2) =========================
  const int fn = tid & 127;
  float v0 = 0.f, v1 = 0.f, v2 = 0.f;
  float zacc = 0.f;

  // ---- phase 1: correlation gate (in-place on Ash) ----
  if (tid < 128) {
    float a0 = Ash[0][fn];
    float a1 = Ash[1][fn];
    float a2 = Ash[2][fn];
    float a3 = Ash[3][fn];
    float n0 = a0*a0;
    float C1 = cvt[C1_OFF + (layer*4 + 0)*NF + fn];
    float C2 = cvt[C2_OFF + (layer*4 + 0)*NF + fn];
    float C3 = cvt[C3_OFF + (layer*4 + 0)*NF + fn];
    float g0 = 1.0f + C1*n0 + C2*n0*n0 + C3*n0*n0*n0;
    float n1 = a1*a1 + a2*a2 + a3*a3;
    float D1 = cvt[C1_OFF + (layer*4 + 1)*NF + fn];
    float D2 = cvt[C2_OFF + (layer*4 + 1)*NF + fn];
    float D3 = cvt[C3_OFF + (layer*4 + 1)*NF + fn];
    float g1 = 1.0f + D1*n1 + D2*n1*n1 + D3*n1*n1*n1;
    Ash[0][fn] = a0 * g0;
    Ash[1][fn] = a1 * g1;
    Ash[2][fn] = a2 * g1;
    Ash[3][fn] = a3 * g1;
  }
  __syncthreads();

  // ---- phase 2: split-k GEMV vs M0 (scalar) and M1 (vector x3) ----
  {
    const float* M0 = cvt + M0_OFF + layer*NF*NF;
    const float* M1 = cvt + M1_OFF + layer*NF*NF;
    const int kh = tid >> 5;        // 0..7
    const int fq = tid & 31;        // f quad: f0 = fq*4
    float s0=0.f,s1=0.f,s2=0.f,s3=0.f;
    float w00=0.f,w01=0.f,w02=0.f,w03=0.f;
    float w10=0.f,w11=0.f,w12=0.f,w13=0.f;
    float w20=0.f,w21=0.f,w22=0.f,w23=0.f;
    #pragma unroll 4
    for (int kk = 0; kk < 16; ++kk) {
      int k = kh*16 + kk;
      float a0 = Ash[0][k], a1 = Ash[1][k], a2 = Ash[2][k], a3 = Ash[3][k];
      float4 m0 = *(const float4*)(M0 + k*NF + fq*4);
      float4 m1 = *(const float4*)(M1 + k*NF + fq*4);
      s0 += a0*m0.x; s1 += a0*m0.y; s2 += a0*m0.z; s3 += a0*m0.w;
      w00 += a1*m1.x; w01 += a1*m1.y; w02 += a1*m1.z; w03 += a1*m1.w;
      w10 += a2*m1.x; w11 += a2*m1.y; w12 += a2*m1.z; w13 += a2*m1.w;
      w20 += a3*m1.x; w21 += a3*m1.y; w22 += a3*m1.z; w23 += a3*m1.w;
    }
    float* Pp = &sm.nd.P[kh][fq][0];
    Pp[0]=s0;  Pp[1]=s1;  Pp[2]=s2;  Pp[3]=s3;
    Pp[4]=w00; Pp[5]=w01; Pp[6]=w02; Pp[7]=w03;
    Pp[8]=w10; Pp[9]=w11; Pp[10]=w12; Pp[11]=w13;
    Pp[12]=w20; Pp[13]=w21; Pp[14]=w22; Pp[15]=w23;
  }
  __syncthreads();

  // ---- phase 3: combine partials; scs + per-thread v0..v2 ----
  if (tid < 128) {
    int fq = fn >> 2, j = fn & 3;
    float sn = 0.f;
    #pragma unroll
    for (int kh = 0; kh < 8; ++kh) {
      const float* Pp = &sm.nd.P[kh][fq][0];
      sn += Pp[j];
      v0 += Pp[4 + j];
      v1 += Pp[8 + j];
      v2 += Pp[12 + j];
    }
    sm.nd.scs[fn] = sn;
  }
  __syncthreads();

  // ---- phase 4: z-GEMV for next layer (split-k) + G1 partials ----
  if (!last) {
    const float* W = cvt + WN_OFF + (layer+1)*NF*NF;
    const int kh = tid >> 5;
    const int fq = tid & 31;
    float s0=0.f,s1=0.f,s2=0.f,s3=0.f;
    #pragma unroll 4
    for (int kk = 0; kk < 16; ++kk) {
      int k = kh*16 + kk;
      float a = sm.nd.scs[k];
      float4 m = *(const float4*)(W + k*NF + fq*4);
      s0 += a*m.x; s1 += a*m.y; s2 += a*m.z; s3 += a*m.w;
    }
    float* Pp = &sm.nd.P[kh][fq][0];
    Pp[0]=s0; Pp[1]=s1; Pp[2]=s2; Pp[3]=s3;
  }
  if (tid < 128) {
    const float* G1 = cvt + G1_OFF + layer*NF*16;
    int o = tid & 15, g = tid >> 4;   // 8 k-groups x 16 outputs
    float acc = 0.f;
    #pragma unroll
    for (int kk = 0; kk < 16; ++kk) {
      int k = g*16 + kk;
      acc += sm.nd.scs[k] * G1[k*16 + o];
    }
    sm.nd.Pg[g][o] = acc;
  }
  __syncthreads();

  // ---- phase 5: combine z partials (kept in register) + h16 ----
  if (!last && tid < 128) {
    int fq = fn >> 2, j = fn & 3;
    #pragma unroll
    for (int kh = 0; kh < 8; ++kh) zacc += sm.nd.P[kh][fq][j];
  }
  if (tid < 16) {
    float acc = 0.f;
    #pragma unroll
    for (int g = 0; g < 8; ++g) acc += sm.nd.Pg[g][tid];
    sm.nd.h16[tid] = silu_fast(acc);
  }
  __syncthreads();

  // ---- phase 6: gate, fused {z,vec} float4 store, position update ----
  if (tid < 128) {
    const float* G2 = cvt + G2_OFF + layer*16*NF;
    float gate = 0.f;
    #pragma unroll
    for (int j = 0; j < 16; ++j)
      gate += sm.nd.h16[j] * G2[j*NF + fn];
    float gv = gate * cvt[WV_OFF + layer*NF + fn];

    if (!last)
      zvOut[(size_t)bidx*NF + fn] = make_float4(zacc, v0, v1, v2);

    float p0 = v0*gv, p1 = v1*gv, p2 = v2*gv;
    #pragma unroll
    for (int off = 32; off > 0; off >>= 1) {
      p0 += __shfl_down(p0, off, 64);
      p1 += __shfl_down(p1, off, 64);
      p2 += __shfl_down(p2, off, 64);
    }
    int wave = fn >> 6;
    if ((fn & 63) == 0) {
      sm.nd.red[wave][0] = p0;
      sm.nd.red[wave][1] = p1;
      sm.nd.red[wave][2] = p2;
    }
  }
  __syncthreads();
  if (tid == 0) {
    float m0 = sm.nd.red[0][0] + sm.nd.red[1][0];
    float m1 = sm.nd.red[0][1] + sm.nd.red[1][1];
    float m2 = sm.nd.red[0][2] + sm.nd.red[1][2];
    float px = posL[n*3+0] + m0;
    float py = posL[n*3+1] + m1;
    float pz = posL[n*3+2] + m2;
    if (!last) {
      posOut[bidx*3+0] = px;
      posOut[bidx*3+1] = py;
      posOut[bidx*3+2] = pz;
    } else {
      float ox = px - cvt[POS_OFF + bidx*3+0];
      float oy = py - cvt[POS_OFF + bidx*3+1];
      float oz = pz - cvt[POS_OFF + bidx*3+2];
      if (*flag) {
        bf16* o = (bf16*)out;
        o[bidx*3+0] = __float2bfloat16(ox);
        o[bidx*3+1] = __float2bfloat16(oy);
        o[bidx*3+2] = __float2bfloat16(oz);
      } else {
        float* o = (float*)out;
        o[bidx*3+0] = ox;
        o[bidx*3+1] = oy;
        o[bidx*3+2] = oz;
      }
    }
  }
}

// ---------------------------------------------------------------------------
extern "C" void kernel_launch(void* const* d_in, const int* in_sizes, int n_in,
                              void* d_out, int out_size, void* d_ws, size_t ws_size,
                              hipStream_t stream)
{
  (void)in_sizes; (void)n_in; (void)out_size; (void)ws_size;
  const int* nfeat = (const int*)d_in[1];

  float*  ws   = (float*)d_ws;
  int*    flag = (int*)ws;                      // 16 floats reserved
  float*  cvt  = ws + 16;                       // CVT_TOTAL floats
  float*  pos0 = cvt + CVT_TOTAL;               // 1536
  float*  pos1 = pos0 + NB*NN*3;                // 1536
  float4* zv0  = (float4*)(pos1 + NB*NN*3);     // NB*NN*NF float4 (16B-aligned)
  float4* zv1  = zv0 + (size_t)NB*NN*NF;        // NB*NN*NF float4
  float*  env  = (float*)(zv1 + (size_t)NB*NN*NF);  // NB*NN*NN
  short*  pk   = (short*)(env + NB*NN*NN);      // 32768 shorts

  prep_convert_kernel<<<512, 256, 0, stream>>>(
      d_in[0], nfeat, d_in[2], d_in[3], d_in[4], d_in[5], d_in[6], d_in[7],
      d_in[8], d_in[9], d_in[10], d_in[11], d_in[12], d_in[13], d_in[14],
      d_in[15], d_in[16], flag, cvt, pos0, zv0, env, pk);

  fused_kernel<<<512, 256, 0, stream>>>(pos0, pos1, zv0, zv1, env, cvt, pk,
                                        0, 0, flag, d_out);
  fused_kernel<<<512, 256, 0, stream>>>(pos1, (float*)0, zv1, (float4*)0, env,
                                        cvt, pk, 1, 1, flag, d_out);
}